// Round 21
// baseline (139.940 us; speedup 1.0000x reference)
//
#include <hip/hip_runtime.h>

#define N_ENT 100000
#define DIM 512
#define RANK 256
#define HROWS 256
#define MAXOBS 32
#define NCT 782            // col tiles of 128 ents
#define NPART (NCT * 2)    // partial slots: (col-tile, wave-col-half)
#define AS1 __attribute__((address_space(1)))
#define AS3 __attribute__((address_space(3)))

typedef __attribute__((ext_vector_type(8))) short short8_t;
typedef __attribute__((ext_vector_type(4))) float f32x4;

__device__ __forceinline__ unsigned short f2bf(float f) {
  unsigned int x = __float_as_uint(f);
  x = x + 0x7fffu + ((x >> 16) & 1u);
  return (unsigned short)(x >> 16);
}
__device__ __forceinline__ float bf2f(unsigned short u) {
  unsigned int x = ((unsigned int)u) << 16;
  return __uint_as_float(x);
}

// ---- mask format handling (bool storage dtype is harness-dependent) ----
__device__ __forceinline__ int mask_mode(const int* flags) {
  int nz0 = flags[0], nz1 = flags[1], nz2 = flags[2], nz3 = flags[3];
  if (nz1 || (nz0 && (nz2 | nz3))) return 0;  // uint8
  if (nz0) return 1;                          // int32
  if (nz2 | nz3) return 2;                    // float32
  return 0;
}

__device__ __forceinline__ int mask_at(const void* mask, int idx, int mode) {
  if (mode == 0) return ((const unsigned char*)mask)[idx] != 0;
  if (mode == 1) return ((const int*)mask)[idx] != 0;
  return ((const float*)mask)[idx] != 0.0f;
}

__global__ void detect_mask_kernel(const unsigned char* __restrict__ mb, int* flags) {
  int t = threadIdx.x;
  int nz[4] = {0, 0, 0, 0};
  for (int j = 0; j < 32; ++j) {
    int idx = t * 32 + j;
    if (mb[idx]) nz[idx & 3] = 1;
  }
  for (int r = 0; r < 4; ++r)
    if (nz[r]) atomicOr(&flags[r], 1);
}

// ---- head extraction ----
__global__ void find_heads_kernel(const float* __restrict__ vec, int* counter, int* tmp) {
  int i = blockIdx.x * blockDim.x + threadIdx.x;
  if (i < N_ENT && vec[i] != 0.0f) {
    int p = atomicAdd(counter, 1);
    if (p < HROWS) tmp[p] = i;
  }
}

__global__ void sort_heads_kernel(const int* __restrict__ counter, const int* __restrict__ tmp,
                                  int* __restrict__ heads) {
  __shared__ int v[HROWS];
  int t = threadIdx.x;
  int cnt = *counter;
  if (cnt > HROWS) cnt = HROWS;
  v[t] = (t < cnt) ? tmp[t] : 0x7fffffff;
  __syncthreads();
  for (int k = 2; k <= HROWS; k <<= 1) {
    for (int j = k >> 1; j > 0; j >>= 1) {
      int ixj = t ^ j;
      if (ixj > t) {
        int a = v[t], b = v[ixj];
        bool up = ((t & k) == 0);
        if ((a > b) == up) { v[t] = b; v[ixj] = a; }
      }
      __syncthreads();
    }
  }
  heads[t] = (v[t] == 0x7fffffff) ? 0 : v[t];
}

// ---- query build (plain row-major bf16) ----
__global__ void build_q_kernel(const float* __restrict__ ent, const float* __restrict__ rel,
                               const int* __restrict__ heads, const int* __restrict__ rel_id,
                               unsigned short* __restrict__ q) {
  int b = blockIdx.x, k = threadIdx.x;
  int h = heads[b];
  const float* r = rel + (size_t)(*rel_id) * (2 * RANK);
  float re_h = ent[(size_t)h * DIM + k];
  float im_h = ent[(size_t)h * DIM + RANK + k];
  float re_r = r[k], im_r = r[RANK + k];
  q[(size_t)b * DIM + k]        = f2bf(re_h * re_r - im_h * im_r);
  q[(size_t)b * DIM + RANK + k] = f2bf(re_h * im_r + im_h * re_r);
}

// ---- GEMM: p_un = exp(q(256x512) @ ent^T); per-(tile,half) partial sums ----
// 782 blocks x 512 thr (8 waves, 4 row x 2 col). Tile 256 rows x 128 ents.
// CHAMPION (R12) drain structure with ONE parameter change: BK 64 -> 32.
// LDS 32KB (A bf16 16KB LINEAR + B f32 16KB swizzled) -> 4 blocks/CU
// (champion had 2): doubled co-residency covers the per-step vmcnt drain.
// A at BK=32 is conflict-free WITHOUT swizzle (addr/16 = row*4+lk is a
// permutation); B keeps the R13-verified slot^(col&7) source swizzle.
template <int MODE>
__global__ __launch_bounds__(512, 4) void gemm_scores_kernel(
    const float* __restrict__ ent, const unsigned short* __restrict__ q,
    float* __restrict__ out, unsigned short* __restrict__ pun,
    float* __restrict__ partial) {
  __shared__ __align__(16) unsigned short As[256 * 32];  // 16 KB bf16, LINEAR
  __shared__ __align__(16) float Bs[128 * 32];           // 16 KB f32, swizzled

  const int t = threadIdx.x;
  const int lane = t & 63;
  const int w = t >> 6;            // wave 0..7
  const int wm = w >> 1;           // row quadrant (64 rows)
  const int wn = w & 1;            // col half (64 cols)
  const int l15 = lane & 15;
  const int lk = lane >> 4;        // 0..3
  const int ct = blockIdx.x;
  const int e0 = ct * 128;

  // staging source offsets (element units; kc added per step). 16B chunks:
  // A: 1024 chunks, n=i*512+t: row=n>>2, slot=n&3, LINEAR source (no swizzle)
  // B: 1024 chunks, n: col=n>>3, slot=n&7, gchunk=slot^(col&7)
  unsigned int offA[2], offB[2];
#pragma unroll
  for (int i = 0; i < 2; ++i) {
    const int n = i * 512 + t;
    {
      const int row = n >> 2, slot = n & 3;
      offA[i] = row * DIM + (slot << 3);
    }
    {
      const int col = n >> 3, slot = n & 7;
      int gcol = e0 + col; if (gcol > N_ENT - 1) gcol = N_ENT - 1;
      offB[i] = (unsigned int)gcol * DIM + ((slot ^ (col & 7)) << 2);
    }
  }

  f32x4 acc[4][4] = {};

#pragma unroll
  for (int kc = 0; kc < DIM; kc += 32) {
    __syncthreads();  // everyone done reading the buffer
#pragma unroll
    for (int i = 0; i < 2; ++i)
      __builtin_amdgcn_global_load_lds(
          (const AS1 void*)(q + offA[i] + kc),
          (AS3 void*)((char*)As + (i * 512 + t) * 16), 16, 0, 0);
#pragma unroll
    for (int i = 0; i < 2; ++i)
      __builtin_amdgcn_global_load_lds(
          (const AS1 void*)(ent + offB[i] + kc),
          (AS3 void*)((char*)Bs + (i * 512 + t) * 16), 16, 0, 0);
    __syncthreads();  // compiler-managed vmcnt drain (m97 structure)

    short8_t a[4];
#pragma unroll
    for (int fr = 0; fr < 4; ++fr) {
      const int row = wm * 64 + fr * 16 + l15;
      a[fr] = *reinterpret_cast<const short8_t*>((const char*)As + row * 64 + lk * 16);
    }
    short8_t b[4];
#pragma unroll
    for (int fb = 0; fb < 4; ++fb) {
      const int col = wn * 64 + fb * 16 + l15;
      const int s0 = (2 * lk) ^ (col & 7);
      const int s1 = (2 * lk + 1) ^ (col & 7);
      float4 f0 = *reinterpret_cast<const float4*>((const char*)Bs + col * 128 + s0 * 16);
      float4 f1 = *reinterpret_cast<const float4*>((const char*)Bs + col * 128 + s1 * 16);
      unsigned int r0, r1, r2, r3;
      asm("v_cvt_pk_bf16_f32 %0, %1, %2" : "=v"(r0) : "v"(f0.x), "v"(f0.y));
      asm("v_cvt_pk_bf16_f32 %0, %1, %2" : "=v"(r1) : "v"(f0.z), "v"(f0.w));
      asm("v_cvt_pk_bf16_f32 %0, %1, %2" : "=v"(r2) : "v"(f1.x), "v"(f1.y));
      asm("v_cvt_pk_bf16_f32 %0, %1, %2" : "=v"(r3) : "v"(f1.z), "v"(f1.w));
      union { unsigned int u[4]; short8_t s8; } bf;
      bf.u[0] = r0; bf.u[1] = r1; bf.u[2] = r2; bf.u[3] = r3;
      b[fb] = bf.s8;
    }
#pragma unroll
    for (int fr = 0; fr < 4; ++fr)
#pragma unroll
      for (int fb = 0; fb < 4; ++fb)
        acc[fr][fb] = __builtin_amdgcn_mfma_f32_16x16x32_bf16(a[fr], b[fb], acc[fr][fb], 0, 0, 0);
  }

  // epilogue: C/D map col=lane&15, row=(lane>>4)*4+reg; store exp(s)
#pragma unroll
  for (int fr = 0; fr < 4; ++fr) {
#pragma unroll
    for (int j = 0; j < 4; ++j) {
      const int grow = wm * 64 + fr * 16 + lk * 4 + j;
      float psum = 0.0f;
#pragma unroll
      for (int fb = 0; fb < 4; ++fb) {
        const int col = e0 + wn * 64 + fb * 16 + l15;
        if (col < N_ENT) {
          float p = __expf(acc[fr][fb][j]);  // |s| small: no max-subtraction
          if (MODE == 0) pun[(size_t)grow * N_ENT + col] = f2bf(p);
          else           out[(size_t)grow * N_ENT + col] = p;
          psum += p;
        }
      }
      psum += __shfl_xor(psum, 1);
      psum += __shfl_xor(psum, 2);
      psum += __shfl_xor(psum, 4);
      psum += __shfl_xor(psum, 8);
      if (l15 == 0) {
        if (MODE == 0) partial[(size_t)(ct * 2 + wn) * HROWS + grow] = psum;
        else atomicAdd(&partial[grow], psum);
      }
    }
  }
}

// ---- fused: rowsum reduce + scaling -> factor[row] ----
template <int MODE>
__global__ void rowscale_kernel(const float* __restrict__ partial,
                                const unsigned short* __restrict__ punb,
                                const float* __restrict__ punf,
                                const int* __restrict__ obs_idx, const void* __restrict__ mask,
                                const int* __restrict__ flags, float* __restrict__ factor) {
  __shared__ float red[256];
  __shared__ float rs_sh;
  const int row = blockIdx.x, t = threadIdx.x;
  if (MODE == 0) {
    float s = 0.0f;
    for (int k = t; k < NPART; k += 256) s += partial[(size_t)k * HROWS + row];
    red[t] = s;
    __syncthreads();
    for (int m = 128; m > 0; m >>= 1) {
      if (t < m) red[t] += red[t + m];
      __syncthreads();
    }
    if (t == 0) rs_sh = red[0];
  } else {
    if (t == 0) rs_sh = partial[row];
  }
  __syncthreads();
  if (t < 32) {
    const int mode = mask_mode(flags);
    const int on = mask_at(mask, row * 32 + t, mode);
    float sume = 0.0f;
    float cntf = 0.0f;
    if (on) {
      const size_t idx = (size_t)row * N_ENT + obs_idx[row * 32 + t];
      sume = (MODE == 0) ? bf2f(punb[idx]) : punf[idx];
      cntf = 1.0f;
    }
#pragma unroll
    for (int m = 1; m < 32; m <<= 1) {
      sume += __shfl_xor(sume, m);
      cntf += __shfl_xor(cntf, m);
    }
    if (t == 0) {
      const float rs = rs_sh;
      float scaling = 1.0f;
      if (cntf > 0.0f) {
        float denom = fmaxf(sume / rs, 1e-30f);
        scaling = cntf / denom;
      }
      factor[row] = scaling / rs;
    }
  }
}

// ---- finalize MODE 0: out = clamp(threshold(bf16 pun * factor)); writes out once ----
__global__ __launch_bounds__(256) void finalize_bf_kernel(const unsigned short* __restrict__ pun,
                                                          float* __restrict__ out,
                                                          const float* __restrict__ factor,
                                                          const int* __restrict__ train) {
  const int row = blockIdx.y;
  const int i8 = blockIdx.x * blockDim.x + threadIdx.x;  // 8 cols per thread
  if (i8 >= N_ENT / 8) return;
  const float f = factor[row];
  const float hi = (*train) ? (1.0f - 0.001f) : 1.0f;
  const short8_t v = *reinterpret_cast<const short8_t*>(pun + (size_t)row * N_ENT + i8 * 8);
  float o[8];
#pragma unroll
  for (int j = 0; j < 8; ++j) {
    float s = bf2f((unsigned short)v[j]) * f;
    s = (s > 1e-4f) ? s : 0.0f;   // THRESHOLD
    o[j] = fminf(s, hi);          // clip(0, hi)
  }
  float4* p = reinterpret_cast<float4*>(out + (size_t)row * N_ENT + i8 * 8);
  p[0] = make_float4(o[0], o[1], o[2], o[3]);
  p[1] = make_float4(o[4], o[5], o[6], o[7]);
}

// ---- finalize MODE 1 (fallback): in-place on f32 out ----
__global__ __launch_bounds__(256) void finalize_kernel(float* __restrict__ out,
                                                       const float* __restrict__ factor,
                                                       const int* __restrict__ train) {
  int row = blockIdx.y;
  int i4 = blockIdx.x * blockDim.x + threadIdx.x;
  if (i4 >= N_ENT / 4) return;
  float f = factor[row];
  float hi = (*train) ? (1.0f - 0.001f) : 1.0f;
  float4* p = reinterpret_cast<float4*>(out + (size_t)row * N_ENT) + i4;
  float4 v = *p;
  float vals[4] = {v.x, v.y, v.z, v.w};
#pragma unroll
  for (int j = 0; j < 4; ++j) {
    float s = vals[j] * f;
    s = (s > 1e-4f) ? s : 0.0f;
    vals[j] = fminf(s, hi);
  }
  v.x = vals[0]; v.y = vals[1]; v.z = vals[2]; v.w = vals[3];
  *p = v;
}

// ---- observed positions -> 1.0 (train only) ----
__global__ void scatter_obs_kernel(float* __restrict__ out, const int* __restrict__ obs_idx,
                                   const void* __restrict__ mask, const int* __restrict__ flags,
                                   const int* __restrict__ train) {
  if (!(*train)) return;
  int t = blockIdx.x * blockDim.x + threadIdx.x;
  if (t >= HROWS * MAXOBS) return;
  int mode = mask_mode(flags);
  if (mask_at(mask, t, mode))
    out[(size_t)(t >> 5) * N_ENT + obs_idx[t]] = 1.0f;
}

extern "C" void kernel_launch(void* const* d_in, const int* in_sizes, int n_in,
                              void* d_out, int out_size, void* d_ws, size_t ws_size,
                              hipStream_t stream) {
  const float* ent      = (const float*)d_in[0];
  const float* rel      = (const float*)d_in[1];
  const float* head_vec = (const float*)d_in[2];
  const int* obs_idx    = (const int*)d_in[3];
  const void* obs_mask  = d_in[4];
  const int* rel_id     = (const int*)d_in[5];
  const int* train      = (const int*)d_in[7];
  float* out = (float*)d_out;

  char* ws = (char*)d_ws;
  int*   counter = (int*)(ws + 0);
  int*   flags   = (int*)(ws + 4);
  float* rowsum  = (float*)(ws + 64);
  float* factor  = (float*)(ws + 1088);
  int*   tmp     = (int*)(ws + 2112);
  int*   heads   = (int*)(ws + 3136);
  unsigned short* q = (unsigned short*)(ws + 4224);   // 256x512 bf16 = 256KB
  unsigned short* pun = (unsigned short*)(ws + 266368);  // 256x100000 bf16 = 51.2MB
  float* partial = (float*)(ws + 266368 + (size_t)HROWS * N_ENT * 2);  // 1.6MB
  const size_t needed = 266368 + (size_t)HROWS * N_ENT * 2 + (size_t)NPART * HROWS * 4;
  const bool big_ws = ws_size >= needed;

  hipMemsetAsync(ws, 0, 2112, stream);  // counter + flags + rowsum

  detect_mask_kernel<<<1, 256, 0, stream>>>((const unsigned char*)obs_mask, flags);
  find_heads_kernel<<<(N_ENT + 255) / 256, 256, 0, stream>>>(head_vec, counter, tmp);
  sort_heads_kernel<<<1, 256, 0, stream>>>(counter, tmp, heads);
  build_q_kernel<<<HROWS, 256, 0, stream>>>(ent, rel, heads, rel_id, q);
  if (big_ws) {
    gemm_scores_kernel<0><<<NCT, 512, 0, stream>>>(ent, q, out, pun, partial);
    rowscale_kernel<0><<<HROWS, 256, 0, stream>>>(partial, pun, nullptr, obs_idx, obs_mask, flags, factor);
    finalize_bf_kernel<<<dim3((N_ENT / 8 + 255) / 256, HROWS), 256, 0, stream>>>(pun, out, factor, train);
  } else {
    gemm_scores_kernel<1><<<NCT, 512, 0, stream>>>(ent, q, out, nullptr, rowsum);
    rowscale_kernel<1><<<HROWS, 256, 0, stream>>>(rowsum, nullptr, out, obs_idx, obs_mask, flags, factor);
    finalize_kernel<<<dim3((N_ENT / 4 + 255) / 256, HROWS), 256, 0, stream>>>(out, factor, train);
  }
  scatter_obs_kernel<<<(HROWS * MAXOBS + 255) / 256, 256, 0, stream>>>(out, obs_idx, obs_mask, flags, train);
}

// Round 22
// 126.596 us; speedup vs baseline: 1.1054x; 1.1054x over previous
//
#include <hip/hip_runtime.h>

#define N_ENT 100000
#define DIM 512
#define RANK 256
#define HROWS 256
#define MAXOBS 32
#define NCT 782            // col tiles of 128 ents
#define NPART (NCT * 2)    // partial slots: (col-tile, wave-col-half)
#define AS1 __attribute__((address_space(1)))
#define AS3 __attribute__((address_space(3)))

typedef __attribute__((ext_vector_type(8))) short short8_t;
typedef __attribute__((ext_vector_type(4))) float f32x4;

__device__ __forceinline__ unsigned short f2bf(float f) {
  unsigned int x = __float_as_uint(f);
  x = x + 0x7fffu + ((x >> 16) & 1u);
  return (unsigned short)(x >> 16);
}
__device__ __forceinline__ float bf2f(unsigned short u) {
  unsigned int x = ((unsigned int)u) << 16;
  return __uint_as_float(x);
}

// ---- mask format handling (bool storage dtype is harness-dependent) ----
__device__ __forceinline__ int mask_mode(const int* flags) {
  int nz0 = flags[0], nz1 = flags[1], nz2 = flags[2], nz3 = flags[3];
  if (nz1 || (nz0 && (nz2 | nz3))) return 0;  // uint8
  if (nz0) return 1;                          // int32
  if (nz2 | nz3) return 2;                    // float32
  return 0;
}

__device__ __forceinline__ int mask_at(const void* mask, int idx, int mode) {
  if (mode == 0) return ((const unsigned char*)mask)[idx] != 0;
  if (mode == 1) return ((const int*)mask)[idx] != 0;
  return ((const float*)mask)[idx] != 0.0f;
}

__global__ void detect_mask_kernel(const unsigned char* __restrict__ mb, int* flags) {
  int t = threadIdx.x;
  int nz[4] = {0, 0, 0, 0};
  for (int j = 0; j < 32; ++j) {
    int idx = t * 32 + j;
    if (mb[idx]) nz[idx & 3] = 1;
  }
  for (int r = 0; r < 4; ++r)
    if (nz[r]) atomicOr(&flags[r], 1);
}

// ---- head extraction ----
__global__ void find_heads_kernel(const float* __restrict__ vec, int* counter, int* tmp) {
  int i = blockIdx.x * blockDim.x + threadIdx.x;
  if (i < N_ENT && vec[i] != 0.0f) {
    int p = atomicAdd(counter, 1);
    if (p < HROWS) tmp[p] = i;
  }
}

__global__ void sort_heads_kernel(const int* __restrict__ counter, const int* __restrict__ tmp,
                                  int* __restrict__ heads) {
  __shared__ int v[HROWS];
  int t = threadIdx.x;
  int cnt = *counter;
  if (cnt > HROWS) cnt = HROWS;
  v[t] = (t < cnt) ? tmp[t] : 0x7fffffff;
  __syncthreads();
  for (int k = 2; k <= HROWS; k <<= 1) {
    for (int j = k >> 1; j > 0; j >>= 1) {
      int ixj = t ^ j;
      if (ixj > t) {
        int a = v[t], b = v[ixj];
        bool up = ((t & k) == 0);
        if ((a > b) == up) { v[t] = b; v[ixj] = a; }
      }
      __syncthreads();
    }
  }
  heads[t] = (v[t] == 0x7fffffff) ? 0 : v[t];
}

// ---- query build (plain row-major bf16) ----
__global__ void build_q_kernel(const float* __restrict__ ent, const float* __restrict__ rel,
                               const int* __restrict__ heads, const int* __restrict__ rel_id,
                               unsigned short* __restrict__ q) {
  int b = blockIdx.x, k = threadIdx.x;
  int h = heads[b];
  const float* r = rel + (size_t)(*rel_id) * (2 * RANK);
  float re_h = ent[(size_t)h * DIM + k];
  float im_h = ent[(size_t)h * DIM + RANK + k];
  float re_r = r[k], im_r = r[RANK + k];
  q[(size_t)b * DIM + k]        = f2bf(re_h * re_r - im_h * im_r);
  q[(size_t)b * DIM + RANK + k] = f2bf(re_h * im_r + im_h * re_r);
}

// ---- GEMM: p_un = exp(q(256x512) @ ent^T); per-(tile,half) partial sums ----
// 782 blocks x 512 thr (8 waves, 4 row x 2 col). Tile 256 rows x 128 ents,
// BK=64, 8 steps, single 64KB buffer (A bf16 32KB + B f32 32KB), 2 blocks/CU.
// m97 structure: {sync; stage 8 gl_lds/thread (LINEAR dest, XOR-swizzled
// SOURCE); sync(drain); ds_read+cvt+32 MFMA}. FINAL CHAMPION (127.1us total):
// 10 alternative schedules/params (counted-vmcnt x2, deep-ring, persistent,
// block-TLP, seq-B, m201-port, no-LDS x2, BK=32) all regressed 6-100us.
template <int MODE>
__global__ __launch_bounds__(512, 4) void gemm_scores_kernel(
    const float* __restrict__ ent, const unsigned short* __restrict__ q,
    float* __restrict__ out, unsigned short* __restrict__ pun,
    float* __restrict__ partial) {
  __shared__ __align__(16) unsigned short As[256 * 64];  // 32 KB bf16, swizzled
  __shared__ __align__(16) float Bs[128 * 64];           // 32 KB f32, swizzled

  const int t = threadIdx.x;
  const int lane = t & 63;
  const int w = t >> 6;            // wave 0..7
  const int wm = w >> 1;           // row quadrant (64 rows)
  const int wn = w & 1;            // col half (64 cols)
  const int l15 = lane & 15;
  const int lk = lane >> 4;        // 0..3
  const int ct = blockIdx.x;
  const int e0 = ct * 128;

  // staging source offsets (element units; kc added per step). 16B chunks:
  // A: 2048 chunks, thread chunk n=i*512+t: row=n>>3, slot=n&7, gchunk=slot^(row&7)
  // B: 2048 chunks, n: col=n>>4, slot=n&15, gchunk=(slot&8)|((slot&7)^(col&7))
  unsigned int offA[4], offB[4];
#pragma unroll
  for (int i = 0; i < 4; ++i) {
    const int n = i * 512 + t;
    {
      const int row = n >> 3, slot = n & 7;
      offA[i] = row * DIM + ((slot ^ (row & 7)) << 3);
    }
    {
      const int col = n >> 4, slot = n & 15;
      int gcol = e0 + col; if (gcol > N_ENT - 1) gcol = N_ENT - 1;
      offB[i] = (unsigned int)gcol * DIM + (((slot & 8) | ((slot & 7) ^ (col & 7))) << 2);
    }
  }

  f32x4 acc[4][4] = {};

#pragma unroll
  for (int kc = 0; kc < DIM; kc += 64) {
    __syncthreads();  // everyone done reading the buffer
#pragma unroll
    for (int i = 0; i < 4; ++i)
      __builtin_amdgcn_global_load_lds(
          (const AS1 void*)(q + offA[i] + kc),
          (AS3 void*)((char*)As + (i * 512 + t) * 16), 16, 0, 0);
#pragma unroll
    for (int i = 0; i < 4; ++i)
      __builtin_amdgcn_global_load_lds(
          (const AS1 void*)(ent + offB[i] + kc),
          (AS3 void*)((char*)Bs + (i * 512 + t) * 16), 16, 0, 0);
    __syncthreads();  // compiler-managed vmcnt drain (m97 structure)

#pragma unroll
    for (int kk = 0; kk < 2; ++kk) {  // two 32-k sub-steps
      short8_t a[4];
#pragma unroll
      for (int fr = 0; fr < 4; ++fr) {
        const int row = wm * 64 + fr * 16 + l15;
        const int slot = (kk * 4 + lk) ^ (row & 7);
        a[fr] = *reinterpret_cast<const short8_t*>((const char*)As + row * 128 + slot * 16);
      }
      short8_t b[4];
#pragma unroll
      for (int fb = 0; fb < 4; ++fb) {
        const int col = wn * 64 + fb * 16 + l15;
        const int c0 = kk * 8 + lk * 2;
        const int s0 = (c0 & 8) | ((c0 & 7) ^ (col & 7));
        const int s1 = ((c0 + 1) & 8) | (((c0 + 1) & 7) ^ (col & 7));
        float4 f0 = *reinterpret_cast<const float4*>((const char*)Bs + col * 256 + s0 * 16);
        float4 f1 = *reinterpret_cast<const float4*>((const char*)Bs + col * 256 + s1 * 16);
        unsigned int r0, r1, r2, r3;
        asm("v_cvt_pk_bf16_f32 %0, %1, %2" : "=v"(r0) : "v"(f0.x), "v"(f0.y));
        asm("v_cvt_pk_bf16_f32 %0, %1, %2" : "=v"(r1) : "v"(f0.z), "v"(f0.w));
        asm("v_cvt_pk_bf16_f32 %0, %1, %2" : "=v"(r2) : "v"(f1.x), "v"(f1.y));
        asm("v_cvt_pk_bf16_f32 %0, %1, %2" : "=v"(r3) : "v"(f1.z), "v"(f1.w));
        union { unsigned int u[4]; short8_t s8; } bf;
        bf.u[0] = r0; bf.u[1] = r1; bf.u[2] = r2; bf.u[3] = r3;
        b[fb] = bf.s8;
      }
#pragma unroll
      for (int fr = 0; fr < 4; ++fr)
#pragma unroll
        for (int fb = 0; fb < 4; ++fb)
          acc[fr][fb] = __builtin_amdgcn_mfma_f32_16x16x32_bf16(a[fr], b[fb], acc[fr][fb], 0, 0, 0);
    }
  }

  // epilogue: C/D map col=lane&15, row=(lane>>4)*4+reg; store exp(s)
#pragma unroll
  for (int fr = 0; fr < 4; ++fr) {
#pragma unroll
    for (int j = 0; j < 4; ++j) {
      const int grow = wm * 64 + fr * 16 + lk * 4 + j;
      float psum = 0.0f;
#pragma unroll
      for (int fb = 0; fb < 4; ++fb) {
        const int col = e0 + wn * 64 + fb * 16 + l15;
        if (col < N_ENT) {
          float p = __expf(acc[fr][fb][j]);  // |s| small: no max-subtraction
          if (MODE == 0) pun[(size_t)grow * N_ENT + col] = f2bf(p);
          else           out[(size_t)grow * N_ENT + col] = p;
          psum += p;
        }
      }
      psum += __shfl_xor(psum, 1);
      psum += __shfl_xor(psum, 2);
      psum += __shfl_xor(psum, 4);
      psum += __shfl_xor(psum, 8);
      if (l15 == 0) {
        if (MODE == 0) partial[(size_t)(ct * 2 + wn) * HROWS + grow] = psum;
        else atomicAdd(&partial[grow], psum);
      }
    }
  }
}

// ---- fused: rowsum reduce + scaling -> factor[row] ----
template <int MODE>
__global__ void rowscale_kernel(const float* __restrict__ partial,
                                const unsigned short* __restrict__ punb,
                                const float* __restrict__ punf,
                                const int* __restrict__ obs_idx, const void* __restrict__ mask,
                                const int* __restrict__ flags, float* __restrict__ factor) {
  __shared__ float red[256];
  __shared__ float rs_sh;
  const int row = blockIdx.x, t = threadIdx.x;
  if (MODE == 0) {
    float s = 0.0f;
    for (int k = t; k < NPART; k += 256) s += partial[(size_t)k * HROWS + row];
    red[t] = s;
    __syncthreads();
    for (int m = 128; m > 0; m >>= 1) {
      if (t < m) red[t] += red[t + m];
      __syncthreads();
    }
    if (t == 0) rs_sh = red[0];
  } else {
    if (t == 0) rs_sh = partial[row];
  }
  __syncthreads();
  if (t < 32) {
    const int mode = mask_mode(flags);
    const int on = mask_at(mask, row * 32 + t, mode);
    float sume = 0.0f;
    float cntf = 0.0f;
    if (on) {
      const size_t idx = (size_t)row * N_ENT + obs_idx[row * 32 + t];
      sume = (MODE == 0) ? bf2f(punb[idx]) : punf[idx];
      cntf = 1.0f;
    }
#pragma unroll
    for (int m = 1; m < 32; m <<= 1) {
      sume += __shfl_xor(sume, m);
      cntf += __shfl_xor(cntf, m);
    }
    if (t == 0) {
      const float rs = rs_sh;
      float scaling = 1.0f;
      if (cntf > 0.0f) {
        float denom = fmaxf(sume / rs, 1e-30f);
        scaling = cntf / denom;
      }
      factor[row] = scaling / rs;
    }
  }
}

// ---- finalize MODE 0: out = clamp(threshold(bf16 pun * factor)); writes out once ----
__global__ __launch_bounds__(256) void finalize_bf_kernel(const unsigned short* __restrict__ pun,
                                                          float* __restrict__ out,
                                                          const float* __restrict__ factor,
                                                          const int* __restrict__ train) {
  const int row = blockIdx.y;
  const int i8 = blockIdx.x * blockDim.x + threadIdx.x;  // 8 cols per thread
  if (i8 >= N_ENT / 8) return;
  const float f = factor[row];
  const float hi = (*train) ? (1.0f - 0.001f) : 1.0f;
  const short8_t v = *reinterpret_cast<const short8_t*>(pun + (size_t)row * N_ENT + i8 * 8);
  float o[8];
#pragma unroll
  for (int j = 0; j < 8; ++j) {
    float s = bf2f((unsigned short)v[j]) * f;
    s = (s > 1e-4f) ? s : 0.0f;   // THRESHOLD
    o[j] = fminf(s, hi);          // clip(0, hi)
  }
  float4* p = reinterpret_cast<float4*>(out + (size_t)row * N_ENT + i8 * 8);
  p[0] = make_float4(o[0], o[1], o[2], o[3]);
  p[1] = make_float4(o[4], o[5], o[6], o[7]);
}

// ---- finalize MODE 1 (fallback): in-place on f32 out ----
__global__ __launch_bounds__(256) void finalize_kernel(float* __restrict__ out,
                                                       const float* __restrict__ factor,
                                                       const int* __restrict__ train) {
  int row = blockIdx.y;
  int i4 = blockIdx.x * blockDim.x + threadIdx.x;
  if (i4 >= N_ENT / 4) return;
  float f = factor[row];
  float hi = (*train) ? (1.0f - 0.001f) : 1.0f;
  float4* p = reinterpret_cast<float4*>(out + (size_t)row * N_ENT) + i4;
  float4 v = *p;
  float vals[4] = {v.x, v.y, v.z, v.w};
#pragma unroll
  for (int j = 0; j < 4; ++j) {
    float s = vals[j] * f;
    s = (s > 1e-4f) ? s : 0.0f;
    vals[j] = fminf(s, hi);
  }
  v.x = vals[0]; v.y = vals[1]; v.z = vals[2]; v.w = vals[3];
  *p = v;
}

// ---- observed positions -> 1.0 (train only) ----
__global__ void scatter_obs_kernel(float* __restrict__ out, const int* __restrict__ obs_idx,
                                   const void* __restrict__ mask, const int* __restrict__ flags,
                                   const int* __restrict__ train) {
  if (!(*train)) return;
  int t = blockIdx.x * blockDim.x + threadIdx.x;
  if (t >= HROWS * MAXOBS) return;
  int mode = mask_mode(flags);
  if (mask_at(mask, t, mode))
    out[(size_t)(t >> 5) * N_ENT + obs_idx[t]] = 1.0f;
}

extern "C" void kernel_launch(void* const* d_in, const int* in_sizes, int n_in,
                              void* d_out, int out_size, void* d_ws, size_t ws_size,
                              hipStream_t stream) {
  const float* ent      = (const float*)d_in[0];
  const float* rel      = (const float*)d_in[1];
  const float* head_vec = (const float*)d_in[2];
  const int* obs_idx    = (const int*)d_in[3];
  const void* obs_mask  = d_in[4];
  const int* rel_id     = (const int*)d_in[5];
  const int* train      = (const int*)d_in[7];
  float* out = (float*)d_out;

  char* ws = (char*)d_ws;
  int*   counter = (int*)(ws + 0);
  int*   flags   = (int*)(ws + 4);
  float* rowsum  = (float*)(ws + 64);
  float* factor  = (float*)(ws + 1088);
  int*   tmp     = (int*)(ws + 2112);
  int*   heads   = (int*)(ws + 3136);
  unsigned short* q = (unsigned short*)(ws + 4224);   // 256x512 bf16 = 256KB
  unsigned short* pun = (unsigned short*)(ws + 266368);  // 256x100000 bf16 = 51.2MB
  float* partial = (float*)(ws + 266368 + (size_t)HROWS * N_ENT * 2);  // 1.6MB
  const size_t needed = 266368 + (size_t)HROWS * N_ENT * 2 + (size_t)NPART * HROWS * 4;
  const bool big_ws = ws_size >= needed;

  hipMemsetAsync(ws, 0, 2112, stream);  // counter + flags + rowsum

  detect_mask_kernel<<<1, 256, 0, stream>>>((const unsigned char*)obs_mask, flags);
  find_heads_kernel<<<(N_ENT + 255) / 256, 256, 0, stream>>>(head_vec, counter, tmp);
  sort_heads_kernel<<<1, 256, 0, stream>>>(counter, tmp, heads);
  build_q_kernel<<<HROWS, 256, 0, stream>>>(ent, rel, heads, rel_id, q);
  if (big_ws) {
    gemm_scores_kernel<0><<<NCT, 512, 0, stream>>>(ent, q, out, pun, partial);
    rowscale_kernel<0><<<HROWS, 256, 0, stream>>>(partial, pun, nullptr, obs_idx, obs_mask, flags, factor);
    finalize_bf_kernel<<<dim3((N_ENT / 8 + 255) / 256, HROWS), 256, 0, stream>>>(pun, out, factor, train);
  } else {
    gemm_scores_kernel<1><<<NCT, 512, 0, stream>>>(ent, q, out, nullptr, rowsum);
    rowscale_kernel<1><<<HROWS, 256, 0, stream>>>(rowsum, nullptr, out, obs_idx, obs_mask, flags, factor);
    finalize_kernel<<<dim3((N_ENT / 4 + 255) / 256, HROWS), 256, 0, stream>>>(out, factor, train);
  }
  scatter_obs_kernel<<<(HROWS * MAXOBS + 255) / 256, 256, 0, stream>>>(out, obs_idx, obs_mask, flags, train);
}